// Round 5
// baseline (655.348 us; speedup 1.0000x reference)
//
#include <hip/hip_runtime.h>
#include <hip/hip_bf16.h>
#include <math.h>

// GATNet: hh = h@W_emb+b_emb -> GAT(8 heads,32,residual) -> GAT(1 head,32) -> out f32.
// Edge-feature branch of the reference is dead code (del e_feat) -> skipped.
// OUTPUT IS FLOAT32 (reference's output dtype; harness rule "bf16->bf16*, else float*").
// Inputs read dual-dtype (bf16 or f32) via device-side sniff flag (evidence: f32).

#define HDIM 256
#define NHEADS 8
#define ODIM 32

typedef unsigned short u16;

__device__ __forceinline__ float bf2f(u16 u) { return __uint_as_float(((unsigned)u) << 16); }
__device__ __forceinline__ u16 f2bf(float f) {
    unsigned x = __float_as_uint(f);
    return (u16)((x + 0x7FFFu + ((x >> 16) & 1u)) >> 16);  // RNE
}
// dual-dtype input read: isbf=1 -> bf16 halfwords, else f32
__device__ __forceinline__ float rdIn(const void* p, long i, int isbf) {
    return isbf ? bf2f(((const u16*)p)[i]) : ((const float*)p)[i];
}

// ---------------- dtype sniff: bf16 inputs vs f32 inputs ----------------
__global__ __launch_bounds__(256) void sniff_kernel(const u16* __restrict__ h16, int* __restrict__ flag) {
    __shared__ float smax[256];
    int t = threadIdx.x;
    float m = 0.f;
    for (int i = t; i < 2048; i += 256) {
        float a = fabsf(bf2f(h16[i]));
        if (!(a < 1e30f)) a = 1e30f;
        m = fmaxf(m, a);
    }
    smax[t] = m;
    __syncthreads();
    if (t == 0) {
        float mm = 0.f;
        for (int j = 0; j < 256; j++) mm = fmaxf(mm, smax[j]);
        *flag = (mm < 1e5f) ? 1 : 0;
    }
}

// ---------------- CSR build (dst -> edge list) ----------------
__global__ __launch_bounds__(256) void deg_kernel(const int* __restrict__ dst, int* __restrict__ deg, int E, int N) {
    int i = blockIdx.x * 256 + threadIdx.x;
    if (i < E) {
        unsigned d = (unsigned)dst[i];
        if (d < (unsigned)N) atomicAdd(&deg[d], 1);
    }
}

__global__ __launch_bounds__(256) void scan_kernel(const int* __restrict__ deg, int* __restrict__ offs,
                                                   int* __restrict__ cursor, int n) {
    __shared__ int part[256];
    int t = threadIdx.x;
    int chunk = (n + 255) / 256;
    int lo = t * chunk, hi = lo + chunk;
    if (hi > n) hi = n;
    if (lo > n) lo = n;
    int s = 0;
    for (int i = lo; i < hi; i++) s += deg[i];
    part[t] = s;
    __syncthreads();
    if (t == 0) {
        int run = 0;
        for (int j = 0; j < 256; j++) { int v = part[j]; part[j] = run; run += v; }
        offs[n] = run;
    }
    __syncthreads();
    int run = part[t];
    for (int i = lo; i < hi; i++) {
        offs[i] = run;
        cursor[i] = run;
        run += deg[i];
    }
}

__global__ __launch_bounds__(256) void fill_kernel(const int* __restrict__ dst, int* __restrict__ cursor,
                                                   int* __restrict__ eidx, int E, int N) {
    int i = blockIdx.x * 256 + threadIdx.x;
    if (i < E) {
        unsigned d = (unsigned)dst[i];
        if (d < (unsigned)N) {
            int p = atomicAdd(&cursor[d], 1);
            if ((unsigned)p < (unsigned)E) eidx[p] = i;
        }
    }
}

// ---------------- GEMMs (naive: one thread per output element) ----------------
__global__ __launch_bounds__(256) void gemm_emb(const void* __restrict__ A, const void* __restrict__ B,
                                                const void* __restrict__ bias, u16* __restrict__ C, int M,
                                                const int* __restrict__ flag) {
    const int isbf = *flag;
    int idx = blockIdx.x * 256 + threadIdx.x;
    if (idx >= M * HDIM) return;
    int r = idx >> 8, c = idx & 255;
    float acc = rdIn(bias, c, isbf);
    for (int k = 0; k < 128; k++) acc += rdIn(A, (long)r * 128 + k, isbf) * rdIn(B, (long)k * 256 + c, isbf);
    C[idx] = f2bf(acc);
}

__global__ __launch_bounds__(256) void gemm_fc1(const u16* __restrict__ A, const void* __restrict__ B,
                                                u16* __restrict__ C, int M, const int* __restrict__ flag) {
    const int isbf = *flag;
    int idx = blockIdx.x * 256 + threadIdx.x;
    if (idx >= M * HDIM) return;
    int r = idx >> 8, c = idx & 255;
    float acc = 0.f;
    for (int k = 0; k < 256; k++) acc += bf2f(A[(long)r * 256 + k]) * rdIn(B, (long)k * 256 + c, isbf);
    C[idx] = f2bf(acc);
}

__global__ __launch_bounds__(256) void gemm_fc2(const u16* __restrict__ A, const void* __restrict__ B,
                                                float* __restrict__ C, int M, const int* __restrict__ flag) {
    const int isbf = *flag;
    int idx = blockIdx.x * 256 + threadIdx.x;
    if (idx >= M * ODIM) return;
    int r = idx >> 5, c = idx & 31;
    float acc = 0.f;
    for (int k = 0; k < 256; k++) acc += bf2f(A[(long)r * 256 + k]) * rdIn(B, (long)k * 32 + c, isbf);
    C[idx] = acc;
}

// ---------------- attention coefficients ----------------
__global__ __launch_bounds__(256) void elr1(const u16* __restrict__ feat, const void* __restrict__ al,
                                            const void* __restrict__ ar, u16* __restrict__ el, u16* __restrict__ er,
                                            int NH, const int* __restrict__ flag) {
    const int isbf = *flag;
    int idx = blockIdx.x * 256 + threadIdx.x;  // n*8+h
    if (idx >= NH) return;
    int h = idx & 7;
    long base = (long)(idx >> 3) * 256 + h * 32;
    float a = 0.f, b = 0.f;
#pragma unroll
    for (int d = 0; d < 32; d++) {
        float fv = bf2f(feat[base + d]);
        a += fv * rdIn(al, h * 32 + d, isbf);
        b += fv * rdIn(ar, h * 32 + d, isbf);
    }
    el[idx] = f2bf(a);
    er[idx] = f2bf(b);
}

__global__ __launch_bounds__(256) void elr2(const float* __restrict__ feat, const void* __restrict__ al,
                                            const void* __restrict__ ar, float* __restrict__ el,
                                            float* __restrict__ er, int n, const int* __restrict__ flag) {
    const int isbf = *flag;
    int idx = blockIdx.x * 256 + threadIdx.x;
    if (idx >= n) return;
    const float* f = feat + (long)idx * 32;
    float a = 0.f, b = 0.f;
#pragma unroll
    for (int d = 0; d < 32; d++) {
        float fv = f[d];
        a += fv * rdIn(al, d, isbf);
        b += fv * rdIn(ar, d, isbf);
    }
    el[idx] = a;
    er[idx] = b;
}

// exp(leaky_relu(l)); logits O(0.1), max-subtraction unnecessary (identical ratios)
__device__ __forceinline__ float edgew(float l) {
    l = (l > 0.f) ? l : 0.2f * l;
    l = fminf(fmaxf(l, -30.f), 30.f);
    return __expf(l);
}

// ---------------- aggregation (CSR gather, softmax folded) ----------------
__global__ __launch_bounds__(256) void agg1(const u16* __restrict__ feat, const u16* __restrict__ el,
                                            const u16* __restrict__ er, const int* __restrict__ offs,
                                            const int* __restrict__ eidx, const int* __restrict__ src,
                                            u16* __restrict__ rst, int N, int E) {
    int node = blockIdx.x;
    int t = threadIdx.x;  // 8 heads x 32 dims
    int h = t >> 5;
    int beg = offs[node], end = offs[node + 1];
    if (beg < 0) beg = 0;
    if (end > E) end = E;
    float ern = bf2f(er[node * 8 + h]);
    float acc = 0.f, sw = 0.f;
    for (int j = beg; j < end; j++) {
        unsigned e = (unsigned)eidx[j];
        if (e >= (unsigned)E) continue;
        unsigned s = (unsigned)src[e];
        if (s >= (unsigned)N) continue;
        float w = edgew(bf2f(el[s * 8 + h]) + ern);
        sw += w;
        acc += w * bf2f(feat[(long)s * 256 + t]);
    }
    rst[(long)node * 256 + t] = f2bf(acc / (sw + 1e-16f));
}

__global__ __launch_bounds__(256) void agg2(const float* __restrict__ feat, const float* __restrict__ el,
                                            const float* __restrict__ er, const int* __restrict__ offs,
                                            const int* __restrict__ eidx, const int* __restrict__ src,
                                            float* __restrict__ rst, int N, int E) {
    int t = threadIdx.x;
    int node = blockIdx.x * 8 + (t >> 5);
    int d = t & 31;
    if (node >= N) return;
    int beg = offs[node], end = offs[node + 1];
    if (beg < 0) beg = 0;
    if (end > E) end = E;
    float ern = er[node];
    float acc = 0.f, sw = 0.f;
    for (int j = beg; j < end; j++) {
        unsigned e = (unsigned)eidx[j];
        if (e >= (unsigned)E) continue;
        unsigned s = (unsigned)src[e];
        if (s >= (unsigned)N) continue;
        float w = edgew(el[s] + ern);
        sw += w;
        acc += w * feat[(long)s * 32 + d];
    }
    rst[(long)node * 32 + d] = acc / (sw + 1e-16f);
}

// ---------------- batchnorm (batch stats) ----------------
__device__ __forceinline__ float ldv(const u16* p, long i) { return bf2f(p[i]); }
__device__ __forceinline__ float ldv(const float* p, long i) { return p[i]; }

template <int C, typename T>
__global__ __launch_bounds__(256) void bn_stats(const T* __restrict__ X, float* __restrict__ stats, int total) {
    int tid = blockIdx.x * 256 + threadIdx.x;
    int stride = gridDim.x * 256;  // multiple of C
    int c = threadIdx.x % C;
    float s = 0.f, s2 = 0.f;
    for (int i = tid; i < total; i += stride) {
        float x = ldv(X, i);
        s += x;
        s2 += x * x;
    }
    atomicAdd(&stats[c], s);
    atomicAdd(&stats[C + c], s2);
}

__global__ __launch_bounds__(256) void bn_apply1(const u16* __restrict__ rst, const float* __restrict__ stats,
                                                 const void* __restrict__ g, const void* __restrict__ b,
                                                 u16* __restrict__ hh, int total, float invN,
                                                 const int* __restrict__ flag) {
    const int isbf = *flag;
    int idx = blockIdx.x * 256 + threadIdx.x;
    if (idx >= total) return;
    int c = idx & 255;
    float mu = stats[c] * invN;
    float var = fmaxf(stats[256 + c] * invN - mu * mu, 0.f);
    float y = rdIn(g, c, isbf) * (bf2f(rst[idx]) - mu) * rsqrtf(var + 1e-5f) + rdIn(b, c, isbf);
    y = (y > 0.f) ? y : expm1f(y);      // elu
    hh[idx] = f2bf(bf2f(hh[idx]) + y);  // residual
}

// FINAL OUTPUT: float32 (reference's output dtype)
__global__ __launch_bounds__(256) void bn_apply2(const float* __restrict__ rst, const float* __restrict__ stats,
                                                 const void* __restrict__ g, const void* __restrict__ b,
                                                 float* __restrict__ out, int total, float invN,
                                                 const int* __restrict__ flag) {
    const int isbf = *flag;
    int idx = blockIdx.x * 256 + threadIdx.x;
    if (idx >= total) return;
    int c = idx & 31;
    float mu = stats[c] * invN;
    float var = fmaxf(stats[32 + c] * invN - mu * mu, 0.f);
    float y = rdIn(g, c, isbf) * (rst[idx] - mu) * rsqrtf(var + 1e-5f) + rdIn(b, c, isbf);
    y = (y > 0.f) ? y : expm1f(y);
    out[idx] = y;
}

extern "C" void kernel_launch(void* const* d_in, const int* in_sizes, int n_in, void* d_out, int out_size, void* d_ws,
                              size_t ws_size, hipStream_t stream) {
    const int N = out_size / ODIM;
    const int E = in_sizes[2];

    const int* src = (const int*)d_in[2];
    const int* dst = (const int*)d_in[3];
    const void* in_h = d_in[0];
    const void* W_emb = d_in[4];  const void* b_emb = d_in[5];
    const void* fc1 = d_in[18];   const void* al1 = d_in[19]; const void* ar1 = d_in[20];
    const void* g1 = d_in[21];    const void* b1 = d_in[22];
    const void* fc2 = d_in[23];   const void* al2 = d_in[24]; const void* ar2 = d_in[25];
    const void* g2 = d_in[26];    const void* b2 = d_in[27];
    float* out = (float*)d_out;

    // ---- compact ws layout (~16.2 MB) ----
    char* base = (char*)d_ws;
    size_t off = 0;
    auto alloc = [&](size_t bytes) { void* p = base + off; off += (bytes + 63) & ~63ull; return p; };
    int* flag  = (int*)alloc(64);
    u16* hh    = (u16*)alloc((size_t)N * HDIM * 2);   // embedding, then +residual
    char* regB = (char*)alloc((size_t)N * HDIM * 2);  // feat1 bf16; layer2: feat2/rst2/el2/er2 f32
    u16* rst   = (u16*)alloc((size_t)N * HDIM * 2);   // layer1 aggregation out
    char* regD = (char*)alloc((size_t)N * NHEADS * 2);  // el1 bf16; earlier: deg (int N)
    char* regE = (char*)alloc((size_t)N * NHEADS * 2);  // er1 bf16; earlier: cursor (int N)
    float* stats = (float*)alloc((2 * HDIM + 2 * ODIM) * 4);
    int* offs  = (int*)alloc((size_t)(N + 1) * 4);
    int* eidx  = (int*)alloc((size_t)E * 4);

    u16* feat1 = (u16*)regB;
    int* deg = (int*)regD;
    int* cursor = (int*)regE;
    u16* el1 = (u16*)regD;
    u16* er1 = (u16*)regE;
    // layer-2 f32 scratch overlaid on regB (feat1 dead after agg1)
    float* feat2 = (float*)regB;
    float* rst2 = feat2 + (size_t)N * ODIM;
    float* el2 = rst2 + (size_t)N * ODIM;
    float* er2 = el2 + N;
    float* stats2 = stats + 2 * HDIM;

    // ---- zero accumulators ----
    hipMemsetAsync(deg, 0, (size_t)N * sizeof(int), stream);
    hipMemsetAsync(stats, 0, (2 * HDIM + 2 * ODIM) * sizeof(float), stream);

    // ---- dtype sniff ----
    sniff_kernel<<<1, 256, 0, stream>>>((const u16*)in_h, flag);

    // ---- CSR by dst ----
    deg_kernel<<<(E + 255) / 256, 256, 0, stream>>>(dst, deg, E, N);
    scan_kernel<<<1, 256, 0, stream>>>(deg, offs, cursor, N);
    fill_kernel<<<(E + 255) / 256, 256, 0, stream>>>(dst, cursor, eidx, E, N);

    // ---- embedding ----
    gemm_emb<<<(N * HDIM + 255) / 256, 256, 0, stream>>>(in_h, W_emb, b_emb, hh, N, flag);

    // ---- GAT layer 1 (8 heads x 32, residual) ----
    gemm_fc1<<<(N * HDIM + 255) / 256, 256, 0, stream>>>(hh, fc1, feat1, N, flag);
    elr1<<<(N * 8 + 255) / 256, 256, 0, stream>>>(feat1, al1, ar1, el1, er1, N * 8, flag);
    agg1<<<N, 256, 0, stream>>>(feat1, el1, er1, offs, eidx, src, rst, N, E);
    bn_stats<256><<<40, 256, 0, stream>>>(rst, stats, N * HDIM);
    bn_apply1<<<(N * HDIM + 255) / 256, 256, 0, stream>>>(rst, stats, g1, b1, hh, N * HDIM, 1.f / N, flag);

    // ---- GAT layer 2 (1 head x 32, no residual) ----
    gemm_fc2<<<(N * ODIM + 255) / 256, 256, 0, stream>>>(hh, fc2, feat2, N, flag);
    elr2<<<(N + 255) / 256, 256, 0, stream>>>(feat2, al2, ar2, el2, er2, N, flag);
    agg2<<<(N + 7) / 8, 256, 0, stream>>>(feat2, el2, er2, offs, eidx, src, rst2, N, E);
    bn_stats<32><<<40, 256, 0, stream>>>(rst2, stats2, N * ODIM);
    bn_apply2<<<(N * ODIM + 255) / 256, 256, 0, stream>>>(rst2, stats2, g2, b2, out, N * ODIM, 1.f / N, flag);
}

// Round 6
// 442.646 us; speedup vs baseline: 1.4805x; 1.4805x over previous
//
#include <hip/hip_runtime.h>
#include <hip/hip_bf16.h>
#include <math.h>

// GATNet: hh = h@W_emb+b_emb -> GAT(8 heads,32,residual) -> GAT(1 head,32) -> out f32.
// Edge-feature branch of the reference is dead code (del e_feat) -> skipped.
// Inputs f32 (proven R1/R5), output f32. Intermediates bf16 (absmax margin 4x).
// R6: register-blocked GEMMs (16 rows/block), hoisted edge weights, no sniff.

#define HDIM 256
#define NHEADS 8
#define ODIM 32

typedef unsigned short u16;

__device__ __forceinline__ float bf2f(u16 u) { return __uint_as_float(((unsigned)u) << 16); }
__device__ __forceinline__ u16 f2bf(float f) {
    unsigned x = __float_as_uint(f);
    return (u16)((x + 0x7FFFu + ((x >> 16) & 1u)) >> 16);  // RNE
}
__device__ __forceinline__ float ldv(const u16* p, long i) { return bf2f(p[i]); }
__device__ __forceinline__ float ldv(const float* p, long i) { return p[i]; }

// ---------------- CSR build (dst -> edge list) ----------------
__global__ __launch_bounds__(256) void deg_kernel(const int* __restrict__ dst, int* __restrict__ deg, int E, int N) {
    int i = blockIdx.x * 256 + threadIdx.x;
    if (i < E) {
        unsigned d = (unsigned)dst[i];
        if (d < (unsigned)N) atomicAdd(&deg[d], 1);
    }
}

__global__ __launch_bounds__(256) void scan_kernel(const int* __restrict__ deg, int* __restrict__ offs,
                                                   int* __restrict__ cursor, int n) {
    __shared__ int part[256];
    int t = threadIdx.x;
    int chunk = (n + 255) / 256;
    int lo = t * chunk, hi = lo + chunk;
    if (hi > n) hi = n;
    if (lo > n) lo = n;
    int s = 0;
    for (int i = lo; i < hi; i++) s += deg[i];
    part[t] = s;
    __syncthreads();
    if (t == 0) {
        int run = 0;
        for (int j = 0; j < 256; j++) { int v = part[j]; part[j] = run; run += v; }
        offs[n] = run;
    }
    __syncthreads();
    int run = part[t];
    for (int i = lo; i < hi; i++) {
        offs[i] = run;
        cursor[i] = run;
        run += deg[i];
    }
}

__global__ __launch_bounds__(256) void fill_kernel(const int* __restrict__ dst, int* __restrict__ cursor,
                                                   int* __restrict__ eidx, int E, int N) {
    int i = blockIdx.x * 256 + threadIdx.x;
    if (i < E) {
        unsigned d = (unsigned)dst[i];
        if (d < (unsigned)N) {
            int p = atomicAdd(&cursor[d], 1);
            if ((unsigned)p < (unsigned)E) eidx[p] = i;
        }
    }
}

// ---------------- GEMM: C[M,256] = A[M,K] @ B[K,256] (+bias), 16 rows/block ----------------
// sA[K][16] transposed in LDS: acc-phase reads are all-lane broadcasts (free);
// staging writes hit 16 distinct banks x2 (2-way = free). B loads coalesced 256B/wave.
template <int K, typename AT>
__global__ __launch_bounds__(256) void gemm16(const AT* __restrict__ A, const float* __restrict__ B,
                                              const float* __restrict__ bias, u16* __restrict__ C, int M) {
    __shared__ __align__(16) float sA[K][16];
    const int t = threadIdx.x;
    const int r0 = blockIdx.x * 16;
    for (int i = t; i < 16 * K; i += 256) {
        int rr = i & 15, kk = i >> 4;
        int r = r0 + rr;
        sA[kk][rr] = (r < M) ? ldv(A, (long)r * K + kk) : 0.f;
    }
    __syncthreads();
    float acc[16];
#pragma unroll
    for (int i = 0; i < 16; i++) acc[i] = 0.f;
    const float4* sA4 = (const float4*)(&sA[0][0]);
#pragma unroll 2
    for (int k = 0; k < K; k++) {
        float bk = B[(long)k * 256 + t];
        float4 a0 = sA4[4 * k + 0];
        float4 a1 = sA4[4 * k + 1];
        float4 a2 = sA4[4 * k + 2];
        float4 a3 = sA4[4 * k + 3];
        acc[0]  += a0.x * bk; acc[1]  += a0.y * bk; acc[2]  += a0.z * bk; acc[3]  += a0.w * bk;
        acc[4]  += a1.x * bk; acc[5]  += a1.y * bk; acc[6]  += a1.z * bk; acc[7]  += a1.w * bk;
        acc[8]  += a2.x * bk; acc[9]  += a2.y * bk; acc[10] += a2.z * bk; acc[11] += a2.w * bk;
        acc[12] += a3.x * bk; acc[13] += a3.y * bk; acc[14] += a3.z * bk; acc[15] += a3.w * bk;
    }
    float bv = bias ? bias[t] : 0.f;
#pragma unroll
    for (int rr = 0; rr < 16; rr++) {
        int r = r0 + rr;
        if (r < M) C[(long)r * 256 + t] = f2bf(acc[rr] + bv);
    }
}

// C[M,32] = A[M,256](bf16) @ B[256,32](f32), f32 out. 8 rows/block.
__global__ __launch_bounds__(256) void gemm_fc2(const u16* __restrict__ A, const float* __restrict__ B,
                                                float* __restrict__ C, int M) {
    __shared__ float sA[8][256];
    const int t = threadIdx.x;
    const int r0 = blockIdx.x * 8;
    for (int i = t; i < 8 * 256; i += 256) {
        int rr = i >> 8, kk = i & 255;
        int r = r0 + rr;
        sA[rr][kk] = (r < M) ? bf2f(A[(long)r * 256 + kk]) : 0.f;
    }
    __syncthreads();
    int c = t & 31, rr = t >> 5;
    float acc = 0.f;
#pragma unroll 8
    for (int k = 0; k < 256; k++) acc += sA[rr][k] * B[k * 32 + c];
    int r = r0 + rr;
    if (r < M) C[(long)r * 32 + c] = acc;
}

// ---------------- attention coefficients ----------------
__global__ __launch_bounds__(256) void elr1(const u16* __restrict__ feat, const float* __restrict__ al,
                                            const float* __restrict__ ar, u16* __restrict__ el,
                                            u16* __restrict__ er, int NH) {
    int idx = blockIdx.x * 256 + threadIdx.x;  // n*8+h
    if (idx >= NH) return;
    int h = idx & 7;
    long base = (long)(idx >> 3) * 256 + h * 32;
    float a = 0.f, b = 0.f;
#pragma unroll
    for (int d = 0; d < 32; d++) {
        float fv = bf2f(feat[base + d]);
        a += fv * al[h * 32 + d];
        b += fv * ar[h * 32 + d];
    }
    el[idx] = f2bf(a);
    er[idx] = f2bf(b);
}

__global__ __launch_bounds__(256) void elr2(const float* __restrict__ feat, const float* __restrict__ al,
                                            const float* __restrict__ ar, float* __restrict__ el,
                                            float* __restrict__ er, int n) {
    int idx = blockIdx.x * 256 + threadIdx.x;
    if (idx >= n) return;
    const float* f = feat + (long)idx * 32;
    float a = 0.f, b = 0.f;
#pragma unroll
    for (int d = 0; d < 32; d++) {
        float fv = f[d];
        a += fv * al[d];
        b += fv * ar[d];
    }
    el[idx] = a;
    er[idx] = b;
}

// exp(leaky_relu(l)); logits O(0.1), max-subtraction unnecessary (identical ratios)
__device__ __forceinline__ float edgew(float l) {
    l = (l > 0.f) ? l : 0.2f * l;
    l = fminf(fmaxf(l, -30.f), 30.f);
    return __expf(l);
}

// ---------------- hoisted per-edge weights ----------------
__global__ __launch_bounds__(256) void ew1_kernel(const int* __restrict__ src, const int* __restrict__ dst,
                                                  const u16* __restrict__ el, const u16* __restrict__ er,
                                                  float* __restrict__ ew, int E, int N) {
    int idx = blockIdx.x * 256 + threadIdx.x;  // e*8+h
    if (idx >= E * 8) return;
    int e = idx >> 3, h = idx & 7;
    unsigned s = (unsigned)src[e], d = (unsigned)dst[e];
    float w = 0.f;
    if (s < (unsigned)N && d < (unsigned)N) w = edgew(bf2f(el[s * 8 + h]) + bf2f(er[d * 8 + h]));
    ew[idx] = w;
}

__global__ __launch_bounds__(256) void ew2_kernel(const int* __restrict__ src, const int* __restrict__ dst,
                                                  const float* __restrict__ el, const float* __restrict__ er,
                                                  float* __restrict__ ew, int E, int N) {
    int e = blockIdx.x * 256 + threadIdx.x;
    if (e >= E) return;
    unsigned s = (unsigned)src[e], d = (unsigned)dst[e];
    float w = 0.f;
    if (s < (unsigned)N && d < (unsigned)N) w = edgew(el[s] + er[d]);
    ew[e] = w;
}

// ---------------- aggregation (CSR gather, weights preloaded) ----------------
__global__ __launch_bounds__(256) void agg1(const u16* __restrict__ feat, const float* __restrict__ ew,
                                            const int* __restrict__ offs, const int* __restrict__ eidx,
                                            const int* __restrict__ src, u16* __restrict__ rst, int N, int E) {
    int node = blockIdx.x;
    int t = threadIdx.x;  // 8 heads x 32 dims
    int h = t >> 5;
    int beg = offs[node], end = offs[node + 1];
    if (beg < 0) beg = 0;
    if (end > E) end = E;
    float acc = 0.f, sw = 0.f;
    for (int j = beg; j < end; j++) {
        unsigned e = (unsigned)eidx[j];
        if (e >= (unsigned)E) continue;
        unsigned s = (unsigned)src[e];
        if (s >= (unsigned)N) continue;
        float w = ew[e * 8 + h];
        sw += w;
        acc += w * bf2f(feat[(long)s * 256 + t]);
    }
    rst[(long)node * 256 + t] = f2bf(acc / (sw + 1e-16f));
}

__global__ __launch_bounds__(256) void agg2(const float* __restrict__ feat, const float* __restrict__ ew,
                                            const int* __restrict__ offs, const int* __restrict__ eidx,
                                            const int* __restrict__ src, float* __restrict__ rst, int N, int E) {
    int t = threadIdx.x;
    int node = blockIdx.x * 8 + (t >> 5);
    int d = t & 31;
    if (node >= N) return;
    int beg = offs[node], end = offs[node + 1];
    if (beg < 0) beg = 0;
    if (end > E) end = E;
    float acc = 0.f, sw = 0.f;
    for (int j = beg; j < end; j++) {
        unsigned e = (unsigned)eidx[j];
        if (e >= (unsigned)E) continue;
        unsigned s = (unsigned)src[e];
        if (s >= (unsigned)N) continue;
        float w = ew[e];
        sw += w;
        acc += w * feat[(long)s * 32 + d];
    }
    rst[(long)node * 32 + d] = acc / (sw + 1e-16f);
}

// ---------------- batchnorm (batch stats) ----------------
template <int C, typename T>
__global__ __launch_bounds__(256) void bn_stats(const T* __restrict__ X, float* __restrict__ stats, int total) {
    int tid = blockIdx.x * 256 + threadIdx.x;
    int stride = gridDim.x * 256;  // multiple of C
    int c = threadIdx.x % C;
    float s = 0.f, s2 = 0.f;
    for (int i = tid; i < total; i += stride) {
        float x = ldv(X, i);
        s += x;
        s2 += x * x;
    }
    atomicAdd(&stats[c], s);
    atomicAdd(&stats[C + c], s2);
}

__global__ __launch_bounds__(256) void bn_apply1(const u16* __restrict__ rst, const float* __restrict__ stats,
                                                 const float* __restrict__ g, const float* __restrict__ b,
                                                 u16* __restrict__ hh, int total, float invN) {
    int idx = blockIdx.x * 256 + threadIdx.x;
    if (idx >= total) return;
    int c = idx & 255;
    float mu = stats[c] * invN;
    float var = fmaxf(stats[256 + c] * invN - mu * mu, 0.f);
    float y = g[c] * (bf2f(rst[idx]) - mu) * rsqrtf(var + 1e-5f) + b[c];
    y = (y > 0.f) ? y : expm1f(y);      // elu
    hh[idx] = f2bf(bf2f(hh[idx]) + y);  // residual
}

// FINAL OUTPUT: float32 (reference's output dtype)
__global__ __launch_bounds__(256) void bn_apply2(const float* __restrict__ rst, const float* __restrict__ stats,
                                                 const float* __restrict__ g, const float* __restrict__ b,
                                                 float* __restrict__ out, int total, float invN) {
    int idx = blockIdx.x * 256 + threadIdx.x;
    if (idx >= total) return;
    int c = idx & 31;
    float mu = stats[c] * invN;
    float var = fmaxf(stats[32 + c] * invN - mu * mu, 0.f);
    float y = g[c] * (rst[idx] - mu) * rsqrtf(var + 1e-5f) + b[c];
    y = (y > 0.f) ? y : expm1f(y);
    out[idx] = y;
}

extern "C" void kernel_launch(void* const* d_in, const int* in_sizes, int n_in, void* d_out, int out_size, void* d_ws,
                              size_t ws_size, hipStream_t stream) {
    const int N = out_size / ODIM;
    const int E = in_sizes[2];

    const int* src = (const int*)d_in[2];
    const int* dst = (const int*)d_in[3];
    const float* in_h = (const float*)d_in[0];
    const float* W_emb = (const float*)d_in[4];  const float* b_emb = (const float*)d_in[5];
    const float* fc1 = (const float*)d_in[18];   const float* al1 = (const float*)d_in[19];
    const float* ar1 = (const float*)d_in[20];
    const float* g1 = (const float*)d_in[21];    const float* b1 = (const float*)d_in[22];
    const float* fc2 = (const float*)d_in[23];   const float* al2 = (const float*)d_in[24];
    const float* ar2 = (const float*)d_in[25];
    const float* g2 = (const float*)d_in[26];    const float* b2 = (const float*)d_in[27];
    float* out = (float*)d_out;

    // ---- ws layout (~20.5 MB; evidence R2-R4 bit-identical => >=38MB available) ----
    char* base = (char*)d_ws;
    size_t off = 0;
    auto alloc = [&](size_t bytes) { void* p = base + off; off += (bytes + 63) & ~63ull; return p; };
    u16* hh    = (u16*)alloc((size_t)N * HDIM * 2);   // embedding, then +residual
    char* regB = (char*)alloc((size_t)N * HDIM * 2);  // feat1 bf16; layer2 overlays f32 scratch
    u16* rst   = (u16*)alloc((size_t)N * HDIM * 2);   // layer1 aggregation out
    char* regD = (char*)alloc((size_t)N * NHEADS * 2);  // deg (int N), then el1 bf16
    char* regE = (char*)alloc((size_t)N * NHEADS * 2);  // cursor (int N), then er1 bf16
    float* stats = (float*)alloc((2 * HDIM + 2 * ODIM) * 4);
    int* offs  = (int*)alloc((size_t)(N + 1) * 4);
    int* eidx  = (int*)alloc((size_t)E * 4);
    float* ew1 = (float*)alloc((size_t)E * NHEADS * 4);  // layer1 edge weights; ew2 overlays

    u16* feat1 = (u16*)regB;
    int* deg = (int*)regD;
    int* cursor = (int*)regE;
    u16* el1 = (u16*)regD;
    u16* er1 = (u16*)regE;
    // layer-2 f32 scratch overlays regB (feat1 dead after agg1)
    float* feat2 = (float*)regB;
    float* rst2 = feat2 + (size_t)N * ODIM;
    float* el2 = rst2 + (size_t)N * ODIM;
    float* er2 = el2 + N;
    float* stats2 = stats + 2 * HDIM;
    float* ew2 = ew1;  // overlays (ew1 dead after agg1)

    // ---- zero accumulators ----
    hipMemsetAsync(deg, 0, (size_t)N * sizeof(int), stream);
    hipMemsetAsync(stats, 0, (2 * HDIM + 2 * ODIM) * sizeof(float), stream);

    // ---- CSR by dst ----
    deg_kernel<<<(E + 255) / 256, 256, 0, stream>>>(dst, deg, E, N);
    scan_kernel<<<1, 256, 0, stream>>>(deg, offs, cursor, N);
    fill_kernel<<<(E + 255) / 256, 256, 0, stream>>>(dst, cursor, eidx, E, N);

    // ---- embedding ----
    gemm16<128, float><<<(N + 15) / 16, 256, 0, stream>>>(in_h, W_emb, b_emb, hh, N);

    // ---- GAT layer 1 (8 heads x 32, residual) ----
    gemm16<256, u16><<<(N + 15) / 16, 256, 0, stream>>>(hh, fc1, nullptr, feat1, N);
    elr1<<<(N * 8 + 255) / 256, 256, 0, stream>>>(feat1, al1, ar1, el1, er1, N * 8);
    ew1_kernel<<<(E * 8 + 255) / 256, 256, 0, stream>>>(src, dst, el1, er1, ew1, E, N);
    agg1<<<N, 256, 0, stream>>>(feat1, ew1, offs, eidx, src, rst, N, E);
    bn_stats<256><<<128, 256, 0, stream>>>(rst, stats, N * HDIM);
    bn_apply1<<<(N * HDIM + 255) / 256, 256, 0, stream>>>(rst, stats, g1, b1, hh, N * HDIM, 1.f / N);

    // ---- GAT layer 2 (1 head x 32, no residual) ----
    gemm_fc2<<<(N + 7) / 8, 256, 0, stream>>>(hh, fc2, feat2, N);
    elr2<<<(N + 255) / 256, 256, 0, stream>>>(feat2, al2, ar2, el2, er2, N);
    ew2_kernel<<<(E + 255) / 256, 256, 0, stream>>>(src, dst, el2, er2, ew2, E, N);
    agg2<<<(N + 7) / 8, 256, 0, stream>>>(feat2, ew2, offs, eidx, src, rst2, N, E);
    bn_stats<32><<<128, 256, 0, stream>>>(rst2, stats2, N * ODIM);
    bn_apply2<<<(N * ODIM + 255) / 256, 256, 0, stream>>>(rst2, stats2, g2, b2, out, N * ODIM, 1.f / N);
}

// Round 7
// 359.374 us; speedup vs baseline: 1.8236x; 1.2317x over previous
//
#include <hip/hip_runtime.h>
#include <hip/hip_bf16.h>
#include <math.h>

// GATNet: hh = h@W_emb+b_emb -> GAT(8 heads,32,residual) -> GAT(1 head,32) -> out f32.
// Edge-feature branch of the reference is dead code (del e_feat) -> skipped.
// Inputs f32, output f32, intermediates bf16 (absmax margin 4x).
// R7: 4x4 register-blocked GEMM (1 ds_read_b128 + 1 float4 B-load per 16 FMA);
//     bn_stats re-parallelized (block-contiguous rows, was 2 waves/CU latency-starved).

#define HDIM 256
#define NHEADS 8
#define ODIM 32

typedef unsigned short u16;

__device__ __forceinline__ float bf2f(u16 u) { return __uint_as_float(((unsigned)u) << 16); }
__device__ __forceinline__ u16 f2bf(float f) {
    unsigned x = __float_as_uint(f);
    return (u16)((x + 0x7FFFu + ((x >> 16) & 1u)) >> 16);  // RNE
}
__device__ __forceinline__ float ldv(const u16* p, long i) { return bf2f(p[i]); }
__device__ __forceinline__ float ldv(const float* p, long i) { return p[i]; }

// ---------------- CSR build (dst -> edge list) ----------------
__global__ __launch_bounds__(256) void deg_kernel(const int* __restrict__ dst, int* __restrict__ deg, int E, int N) {
    int i = blockIdx.x * 256 + threadIdx.x;
    if (i < E) {
        unsigned d = (unsigned)dst[i];
        if (d < (unsigned)N) atomicAdd(&deg[d], 1);
    }
}

__global__ __launch_bounds__(256) void scan_kernel(const int* __restrict__ deg, int* __restrict__ offs,
                                                   int* __restrict__ cursor, int n) {
    __shared__ int part[256];
    int t = threadIdx.x;
    int chunk = (n + 255) / 256;
    int lo = t * chunk, hi = lo + chunk;
    if (hi > n) hi = n;
    if (lo > n) lo = n;
    int s = 0;
    for (int i = lo; i < hi; i++) s += deg[i];
    part[t] = s;
    __syncthreads();
    if (t == 0) {
        int run = 0;
        for (int j = 0; j < 256; j++) { int v = part[j]; part[j] = run; run += v; }
        offs[n] = run;
    }
    __syncthreads();
    int run = part[t];
    for (int i = lo; i < hi; i++) {
        offs[i] = run;
        cursor[i] = run;
        run += deg[i];
    }
}

__global__ __launch_bounds__(256) void fill_kernel(const int* __restrict__ dst, int* __restrict__ cursor,
                                                   int* __restrict__ eidx, int E, int N) {
    int i = blockIdx.x * 256 + threadIdx.x;
    if (i < E) {
        unsigned d = (unsigned)dst[i];
        if (d < (unsigned)N) {
            int p = atomicAdd(&cursor[d], 1);
            if ((unsigned)p < (unsigned)E) eidx[p] = i;
        }
    }
}

// ---------------- GEMM: C[M,256] = A[M,K] @ B[K,256] (+bias) ----------------
// 16 rows/block, 4x4 register tile per thread. Per k: 1 float4 B-load (coalesced,
// 16B/lane), 1 broadcast ds_read_b128 (free), 16 FMAs -> VALU-bound.
template <int K, typename AT>
__global__ __launch_bounds__(256) void gemm_rb(const AT* __restrict__ A, const float* __restrict__ B,
                                               const float* __restrict__ bias, u16* __restrict__ C, int M) {
    __shared__ __align__(16) float sA[K][16];
    const int t = threadIdx.x;
    const int r0 = blockIdx.x * 16;
    // staging (proven conflict-free): lanes write words kk*16+rr -> 2-way max
    for (int i = t; i < 16 * K; i += 256) {
        int rr = i & 15, kk = i >> 4;
        int r = r0 + rr;
        sA[kk][rr] = (r < M) ? ldv(A, (long)r * K + kk) : 0.f;
    }
    __syncthreads();
    const int cg = t & 63;   // col group: cols 4*cg .. +3
    const int rg = t >> 6;   // row group: rows r0+4*rg .. +3 (wave-uniform)
    const float4* B4 = (const float4*)B;
    const float4* sA4 = (const float4*)(&sA[0][0]);
    float acc[4][4];
#pragma unroll
    for (int i = 0; i < 4; i++)
#pragma unroll
        for (int j = 0; j < 4; j++) acc[i][j] = 0.f;
#pragma unroll 4
    for (int k = 0; k < K; k++) {
        float4 b = B4[k * 64 + cg];      // B[k][4cg..4cg+3]
        float4 a = sA4[k * 4 + rg];      // sA[k][4rg..4rg+3], broadcast
        acc[0][0] += a.x * b.x; acc[0][1] += a.x * b.y; acc[0][2] += a.x * b.z; acc[0][3] += a.x * b.w;
        acc[1][0] += a.y * b.x; acc[1][1] += a.y * b.y; acc[1][2] += a.y * b.z; acc[1][3] += a.y * b.w;
        acc[2][0] += a.z * b.x; acc[2][1] += a.z * b.y; acc[2][2] += a.z * b.z; acc[2][3] += a.z * b.w;
        acc[3][0] += a.w * b.x; acc[3][1] += a.w * b.y; acc[3][2] += a.w * b.z; acc[3][3] += a.w * b.w;
    }
    float4 bv = {0.f, 0.f, 0.f, 0.f};
    if (bias) bv = ((const float4*)bias)[cg];
#pragma unroll
    for (int i = 0; i < 4; i++) {
        int r = r0 + rg * 4 + i;
        if (r < M) {
            ushort4 uo;
            uo.x = f2bf(acc[i][0] + bv.x);
            uo.y = f2bf(acc[i][1] + bv.y);
            uo.z = f2bf(acc[i][2] + bv.z);
            uo.w = f2bf(acc[i][3] + bv.w);
            *(ushort4*)(C + (long)r * 256 + cg * 4) = uo;
        }
    }
}

// C[M,32] = A[M,256](bf16) @ B[256,32](f32), f32 out. 8 rows/block.
__global__ __launch_bounds__(256) void gemm_fc2(const u16* __restrict__ A, const float* __restrict__ B,
                                                float* __restrict__ C, int M) {
    __shared__ float sA[8][256];
    const int t = threadIdx.x;
    const int r0 = blockIdx.x * 8;
    for (int i = t; i < 8 * 256; i += 256) {
        int rr = i >> 8, kk = i & 255;
        int r = r0 + rr;
        sA[rr][kk] = (r < M) ? bf2f(A[(long)r * 256 + kk]) : 0.f;
    }
    __syncthreads();
    int c = t & 31, rr = t >> 5;
    float acc = 0.f;
#pragma unroll 8
    for (int k = 0; k < 256; k++) acc += sA[rr][k] * B[k * 32 + c];
    int r = r0 + rr;
    if (r < M) C[(long)r * 32 + c] = acc;
}

// ---------------- attention coefficients ----------------
__global__ __launch_bounds__(256) void elr1(const u16* __restrict__ feat, const float* __restrict__ al,
                                            const float* __restrict__ ar, u16* __restrict__ el,
                                            u16* __restrict__ er, int NH) {
    int idx = blockIdx.x * 256 + threadIdx.x;  // n*8+h
    if (idx >= NH) return;
    int h = idx & 7;
    long base = (long)(idx >> 3) * 256 + h * 32;
    float a = 0.f, b = 0.f;
#pragma unroll
    for (int d = 0; d < 32; d++) {
        float fv = bf2f(feat[base + d]);
        a += fv * al[h * 32 + d];
        b += fv * ar[h * 32 + d];
    }
    el[idx] = f2bf(a);
    er[idx] = f2bf(b);
}

__global__ __launch_bounds__(256) void elr2(const float* __restrict__ feat, const float* __restrict__ al,
                                            const float* __restrict__ ar, float* __restrict__ el,
                                            float* __restrict__ er, int n) {
    int idx = blockIdx.x * 256 + threadIdx.x;
    if (idx >= n) return;
    const float* f = feat + (long)idx * 32;
    float a = 0.f, b = 0.f;
#pragma unroll
    for (int d = 0; d < 32; d++) {
        float fv = f[d];
        a += fv * al[d];
        b += fv * ar[d];
    }
    el[idx] = a;
    er[idx] = b;
}

// exp(leaky_relu(l)); logits O(0.1), max-subtraction unnecessary (identical ratios)
__device__ __forceinline__ float edgew(float l) {
    l = (l > 0.f) ? l : 0.2f * l;
    l = fminf(fmaxf(l, -30.f), 30.f);
    return __expf(l);
}

// ---------------- hoisted per-edge weights ----------------
__global__ __launch_bounds__(256) void ew1_kernel(const int* __restrict__ src, const int* __restrict__ dst,
                                                  const u16* __restrict__ el, const u16* __restrict__ er,
                                                  float* __restrict__ ew, int E, int N) {
    int idx = blockIdx.x * 256 + threadIdx.x;  // e*8+h
    if (idx >= E * 8) return;
    int e = idx >> 3, h = idx & 7;
    unsigned s = (unsigned)src[e], d = (unsigned)dst[e];
    float w = 0.f;
    if (s < (unsigned)N && d < (unsigned)N) w = edgew(bf2f(el[s * 8 + h]) + bf2f(er[d * 8 + h]));
    ew[idx] = w;
}

__global__ __launch_bounds__(256) void ew2_kernel(const int* __restrict__ src, const int* __restrict__ dst,
                                                  const float* __restrict__ el, const float* __restrict__ er,
                                                  float* __restrict__ ew, int E, int N) {
    int e = blockIdx.x * 256 + threadIdx.x;
    if (e >= E) return;
    unsigned s = (unsigned)src[e], d = (unsigned)dst[e];
    float w = 0.f;
    if (s < (unsigned)N && d < (unsigned)N) w = edgew(el[s] + er[d]);
    ew[e] = w;
}

// ---------------- aggregation (CSR gather, weights preloaded) ----------------
__global__ __launch_bounds__(256) void agg1(const u16* __restrict__ feat, const float* __restrict__ ew,
                                            const int* __restrict__ offs, const int* __restrict__ eidx,
                                            const int* __restrict__ src, u16* __restrict__ rst, int N, int E) {
    int node = blockIdx.x;
    int t = threadIdx.x;  // 8 heads x 32 dims
    int h = t >> 5;
    int beg = offs[node], end = offs[node + 1];
    if (beg < 0) beg = 0;
    if (end > E) end = E;
    float acc = 0.f, sw = 0.f;
    for (int j = beg; j < end; j++) {
        unsigned e = (unsigned)eidx[j];
        if (e >= (unsigned)E) continue;
        unsigned s = (unsigned)src[e];
        if (s >= (unsigned)N) continue;
        float w = ew[e * 8 + h];
        sw += w;
        acc += w * bf2f(feat[(long)s * 256 + t]);
    }
    rst[(long)node * 256 + t] = f2bf(acc / (sw + 1e-16f));
}

__global__ __launch_bounds__(256) void agg2(const float* __restrict__ feat, const float* __restrict__ ew,
                                            const int* __restrict__ offs, const int* __restrict__ eidx,
                                            const int* __restrict__ src, float* __restrict__ rst, int N, int E) {
    int t = threadIdx.x;
    int node = blockIdx.x * 8 + (t >> 5);
    int d = t & 31;
    if (node >= N) return;
    int beg = offs[node], end = offs[node + 1];
    if (beg < 0) beg = 0;
    if (end > E) end = E;
    float acc = 0.f, sw = 0.f;
    for (int j = beg; j < end; j++) {
        unsigned e = (unsigned)eidx[j];
        if (e >= (unsigned)E) continue;
        unsigned s = (unsigned)src[e];
        if (s >= (unsigned)N) continue;
        float w = ew[e];
        sw += w;
        acc += w * feat[(long)s * 32 + d];
    }
    rst[(long)node * 32 + d] = acc / (sw + 1e-16f);
}

// ---------------- batchnorm stats (block-contiguous rows, parallel) ----------------
// C=256: thread t = channel t; block covers RPB consecutive rows.
__global__ __launch_bounds__(256) void bn_stats256(const u16* __restrict__ X, float* __restrict__ stats,
                                                   int rows, int RPB) {
    int t = threadIdx.x;
    int rbeg = blockIdx.x * RPB;
    int rend = rbeg + RPB;
    if (rend > rows) rend = rows;
    float s = 0.f, s2 = 0.f;
    for (int r = rbeg; r < rend; r++) {
        float x = bf2f(X[(long)r * 256 + t]);
        s += x;
        s2 += x * x;
    }
    atomicAdd(&stats[t], s);
    atomicAdd(&stats[256 + t], s2);
}

// C=32: 8 row-lanes per channel, LDS-reduce, 1 atomic per channel per block.
__global__ __launch_bounds__(256) void bn_stats32(const float* __restrict__ X, float* __restrict__ stats,
                                                  int rows, int RPB) {
    __shared__ float ss[256], ss2[256];
    int t = threadIdx.x, c = t & 31, rs = t >> 5;
    int rbeg = blockIdx.x * RPB;
    int rend = rbeg + RPB;
    if (rend > rows) rend = rows;
    float s = 0.f, s2 = 0.f;
    for (int r = rbeg + rs; r < rend; r += 8) {
        float x = X[(long)r * 32 + c];
        s += x;
        s2 += x * x;
    }
    ss[t] = s;
    ss2[t] = s2;
    __syncthreads();
    if (t < 32) {
        for (int j = 32; j < 256; j += 32) { s += ss[t + j]; s2 += ss2[t + j]; }
        atomicAdd(&stats[c], s);
        atomicAdd(&stats[32 + c], s2);
    }
}

__global__ __launch_bounds__(256) void bn_apply1(const u16* __restrict__ rst, const float* __restrict__ stats,
                                                 const float* __restrict__ g, const float* __restrict__ b,
                                                 u16* __restrict__ hh, int total, float invN) {
    int idx = blockIdx.x * 256 + threadIdx.x;
    if (idx >= total) return;
    int c = idx & 255;
    float mu = stats[c] * invN;
    float var = fmaxf(stats[256 + c] * invN - mu * mu, 0.f);
    float y = g[c] * (bf2f(rst[idx]) - mu) * rsqrtf(var + 1e-5f) + b[c];
    y = (y > 0.f) ? y : expm1f(y);      // elu
    hh[idx] = f2bf(bf2f(hh[idx]) + y);  // residual
}

// FINAL OUTPUT: float32 (reference's output dtype)
__global__ __launch_bounds__(256) void bn_apply2(const float* __restrict__ rst, const float* __restrict__ stats,
                                                 const float* __restrict__ g, const float* __restrict__ b,
                                                 float* __restrict__ out, int total, float invN) {
    int idx = blockIdx.x * 256 + threadIdx.x;
    if (idx >= total) return;
    int c = idx & 31;
    float mu = stats[c] * invN;
    float var = fmaxf(stats[32 + c] * invN - mu * mu, 0.f);
    float y = g[c] * (rst[idx] - mu) * rsqrtf(var + 1e-5f) + b[c];
    y = (y > 0.f) ? y : expm1f(y);
    out[idx] = y;
}

extern "C" void kernel_launch(void* const* d_in, const int* in_sizes, int n_in, void* d_out, int out_size, void* d_ws,
                              size_t ws_size, hipStream_t stream) {
    const int N = out_size / ODIM;
    const int E = in_sizes[2];

    const int* src = (const int*)d_in[2];
    const int* dst = (const int*)d_in[3];
    const float* in_h = (const float*)d_in[0];
    const float* W_emb = (const float*)d_in[4];  const float* b_emb = (const float*)d_in[5];
    const float* fc1 = (const float*)d_in[18];   const float* al1 = (const float*)d_in[19];
    const float* ar1 = (const float*)d_in[20];
    const float* g1 = (const float*)d_in[21];    const float* b1 = (const float*)d_in[22];
    const float* fc2 = (const float*)d_in[23];   const float* al2 = (const float*)d_in[24];
    const float* ar2 = (const float*)d_in[25];
    const float* g2 = (const float*)d_in[26];    const float* b2 = (const float*)d_in[27];
    float* out = (float*)d_out;

    // ---- ws layout (~20.5 MB) ----
    char* base = (char*)d_ws;
    size_t off = 0;
    auto alloc = [&](size_t bytes) { void* p = base + off; off += (bytes + 63) & ~63ull; return p; };
    u16* hh    = (u16*)alloc((size_t)N * HDIM * 2);
    char* regB = (char*)alloc((size_t)N * HDIM * 2);
    u16* rst   = (u16*)alloc((size_t)N * HDIM * 2);
    char* regD = (char*)alloc((size_t)N * NHEADS * 2);
    char* regE = (char*)alloc((size_t)N * NHEADS * 2);
    float* stats = (float*)alloc((2 * HDIM + 2 * ODIM) * 4);
    int* offs  = (int*)alloc((size_t)(N + 1) * 4);
    int* eidx  = (int*)alloc((size_t)E * 4);
    float* ew1 = (float*)alloc((size_t)E * NHEADS * 4);

    u16* feat1 = (u16*)regB;
    int* deg = (int*)regD;
    int* cursor = (int*)regE;
    u16* el1 = (u16*)regD;
    u16* er1 = (u16*)regE;
    float* feat2 = (float*)regB;
    float* rst2 = feat2 + (size_t)N * ODIM;
    float* el2 = rst2 + (size_t)N * ODIM;
    float* er2 = el2 + N;
    float* stats2 = stats + 2 * HDIM;
    float* ew2 = ew1;

    hipMemsetAsync(deg, 0, (size_t)N * sizeof(int), stream);
    hipMemsetAsync(stats, 0, (2 * HDIM + 2 * ODIM) * sizeof(float), stream);

    // ---- CSR by dst ----
    deg_kernel<<<(E + 255) / 256, 256, 0, stream>>>(dst, deg, E, N);
    scan_kernel<<<1, 256, 0, stream>>>(deg, offs, cursor, N);
    fill_kernel<<<(E + 255) / 256, 256, 0, stream>>>(dst, cursor, eidx, E, N);

    // ---- embedding ----
    gemm_rb<128, float><<<(N + 15) / 16, 256, 0, stream>>>(in_h, W_emb, b_emb, hh, N);

    // ---- GAT layer 1 (8 heads x 32, residual) ----
    gemm_rb<256, u16><<<(N + 15) / 16, 256, 0, stream>>>(hh, fc1, nullptr, feat1, N);
    elr1<<<(N * 8 + 255) / 256, 256, 0, stream>>>(feat1, al1, ar1, el1, er1, N * 8);
    ew1_kernel<<<(E * 8 + 255) / 256, 256, 0, stream>>>(src, dst, el1, er1, ew1, E, N);
    agg1<<<N, 256, 0, stream>>>(feat1, ew1, offs, eidx, src, rst, N, E);
    bn_stats256<<<(N + 39) / 40, 256, 0, stream>>>(rst, stats, N, 40);
    bn_apply1<<<(N * HDIM + 255) / 256, 256, 0, stream>>>(rst, stats, g1, b1, hh, N * HDIM, 1.f / N);

    // ---- GAT layer 2 (1 head x 32, no residual) ----
    gemm_fc2<<<(N + 7) / 8, 256, 0, stream>>>(hh, fc2, feat2, N);
    elr2<<<(N + 255) / 256, 256, 0, stream>>>(feat2, al2, ar2, el2, er2, N);
    ew2_kernel<<<(E + 255) / 256, 256, 0, stream>>>(src, dst, el2, er2, ew2, E, N);
    agg2<<<(N + 7) / 8, 256, 0, stream>>>(feat2, ew2, offs, eidx, src, rst2, N, E);
    bn_stats32<<<(N + 63) / 64, 256, 0, stream>>>(rst2, stats2, N, 64);
    bn_apply2<<<(N * ODIM + 255) / 256, 256, 0, stream>>>(rst2, stats2, g2, b2, out, N * ODIM, 1.f / N);
}

// Round 8
// 334.177 us; speedup vs baseline: 1.9611x; 1.0754x over previous
//
#include <hip/hip_runtime.h>
#include <hip/hip_bf16.h>
#include <math.h>

// GATNet: hh = h@W_emb+b_emb -> GAT(8 heads,32,residual) -> GAT(1 head,32) -> out f32.
// Edge-feature branch of the reference is dead code (del e_feat) -> skipped.
// Inputs f32, output f32, intermediates bf16 (absmax margin 4x).
// R8: agg1 wave-per-node (ushort4: full 512B row per wave-instr), CSR payload arrays
//     srcs/dsts (no eidx chain), slot-ordered edge weights, gemm_fc2 LDS pad.

#define HDIM 256
#define NHEADS 8
#define ODIM 32

typedef unsigned short u16;

__device__ __forceinline__ float bf2f(u16 u) { return __uint_as_float(((unsigned)u) << 16); }
__device__ __forceinline__ u16 f2bf(float f) {
    unsigned x = __float_as_uint(f);
    return (u16)((x + 0x7FFFu + ((x >> 16) & 1u)) >> 16);  // RNE
}
__device__ __forceinline__ float ldv(const u16* p, long i) { return bf2f(p[i]); }
__device__ __forceinline__ float ldv(const float* p, long i) { return p[i]; }

// ---------------- CSR build (dst -> slot-ordered srcs/dsts) ----------------
__global__ __launch_bounds__(256) void deg_kernel(const int* __restrict__ dst, int* __restrict__ deg, int E, int N) {
    int i = blockIdx.x * 256 + threadIdx.x;
    if (i < E) {
        unsigned d = (unsigned)dst[i];
        if (d < (unsigned)N) atomicAdd(&deg[d], 1);
    }
}

__global__ __launch_bounds__(256) void scan_kernel(const int* __restrict__ deg, int* __restrict__ offs,
                                                   int* __restrict__ cursor, int n) {
    __shared__ int part[256];
    int t = threadIdx.x;
    int chunk = (n + 255) / 256;
    int lo = t * chunk, hi = lo + chunk;
    if (hi > n) hi = n;
    if (lo > n) lo = n;
    int s = 0;
    for (int i = lo; i < hi; i++) s += deg[i];
    part[t] = s;
    __syncthreads();
    if (t == 0) {
        int run = 0;
        for (int j = 0; j < 256; j++) { int v = part[j]; part[j] = run; run += v; }
        offs[n] = run;
    }
    __syncthreads();
    int run = part[t];
    for (int i = lo; i < hi; i++) {
        offs[i] = run;
        cursor[i] = run;
        run += deg[i];
    }
}

__global__ __launch_bounds__(256) void fill_kernel(const int* __restrict__ src, const int* __restrict__ dst,
                                                   int* __restrict__ cursor, int* __restrict__ srcs,
                                                   int* __restrict__ dsts, int E, int N) {
    int i = blockIdx.x * 256 + threadIdx.x;
    if (i < E) {
        unsigned d = (unsigned)dst[i];
        if (d < (unsigned)N) {
            int p = atomicAdd(&cursor[d], 1);
            if ((unsigned)p < (unsigned)E) { srcs[p] = src[i]; dsts[p] = (int)d; }
        }
    }
}

// ---------------- GEMM: C[M,256] = A[M,K] @ B[K,256] (+bias) ----------------
// 16 rows/block, 4x4 register tile per thread. Per k: 1 float4 B-load, 1 broadcast
// ds_read_b128, 16 FMAs -> VALU-bound.
template <int K, typename AT>
__global__ __launch_bounds__(256) void gemm_rb(const AT* __restrict__ A, const float* __restrict__ B,
                                               const float* __restrict__ bias, u16* __restrict__ C, int M) {
    __shared__ __align__(16) float sA[K][16];
    const int t = threadIdx.x;
    const int r0 = blockIdx.x * 16;
    for (int i = t; i < 16 * K; i += 256) {
        int rr = i & 15, kk = i >> 4;
        int r = r0 + rr;
        sA[kk][rr] = (r < M) ? ldv(A, (long)r * K + kk) : 0.f;
    }
    __syncthreads();
    const int cg = t & 63;   // cols 4*cg..+3
    const int rg = t >> 6;   // rows r0+4*rg..+3 (wave-uniform)
    const float4* B4 = (const float4*)B;
    const float4* sA4 = (const float4*)(&sA[0][0]);
    float acc[4][4];
#pragma unroll
    for (int i = 0; i < 4; i++)
#pragma unroll
        for (int j = 0; j < 4; j++) acc[i][j] = 0.f;
#pragma unroll 4
    for (int k = 0; k < K; k++) {
        float4 b = B4[k * 64 + cg];
        float4 a = sA4[k * 4 + rg];
        acc[0][0] += a.x * b.x; acc[0][1] += a.x * b.y; acc[0][2] += a.x * b.z; acc[0][3] += a.x * b.w;
        acc[1][0] += a.y * b.x; acc[1][1] += a.y * b.y; acc[1][2] += a.y * b.z; acc[1][3] += a.y * b.w;
        acc[2][0] += a.z * b.x; acc[2][1] += a.z * b.y; acc[2][2] += a.z * b.z; acc[2][3] += a.z * b.w;
        acc[3][0] += a.w * b.x; acc[3][1] += a.w * b.y; acc[3][2] += a.w * b.z; acc[3][3] += a.w * b.w;
    }
    float4 bv = {0.f, 0.f, 0.f, 0.f};
    if (bias) bv = ((const float4*)bias)[cg];
#pragma unroll
    for (int i = 0; i < 4; i++) {
        int r = r0 + rg * 4 + i;
        if (r < M) {
            ushort4 uo;
            uo.x = f2bf(acc[i][0] + bv.x);
            uo.y = f2bf(acc[i][1] + bv.y);
            uo.z = f2bf(acc[i][2] + bv.z);
            uo.w = f2bf(acc[i][3] + bv.w);
            *(ushort4*)(C + (long)r * 256 + cg * 4) = uo;
        }
    }
}

// C[M,32] = A[M,256](bf16) @ B[256,32](f32), f32 out. 8 rows/block.
// LDS padded to 260: banks (4rr+k)%32 -> conflict-free (was 8-way on stride 256).
__global__ __launch_bounds__(256) void gemm_fc2(const u16* __restrict__ A, const float* __restrict__ B,
                                                float* __restrict__ C, int M) {
    __shared__ float sA[8][260];
    const int t = threadIdx.x;
    const int r0 = blockIdx.x * 8;
    for (int i = t; i < 8 * 256; i += 256) {
        int rr = i >> 8, kk = i & 255;
        int r = r0 + rr;
        sA[rr][kk] = (r < M) ? bf2f(A[(long)r * 256 + kk]) : 0.f;
    }
    __syncthreads();
    int c = t & 31, rr = t >> 5;
    float acc = 0.f;
#pragma unroll 8
    for (int k = 0; k < 256; k++) acc += sA[rr][k] * B[k * 32 + c];
    int r = r0 + rr;
    if (r < M) C[(long)r * 32 + c] = acc;
}

// ---------------- attention coefficients ----------------
__global__ __launch_bounds__(256) void elr1(const u16* __restrict__ feat, const float* __restrict__ al,
                                            const float* __restrict__ ar, u16* __restrict__ el,
                                            u16* __restrict__ er, int NH) {
    int idx = blockIdx.x * 256 + threadIdx.x;  // n*8+h
    if (idx >= NH) return;
    int h = idx & 7;
    long base = (long)(idx >> 3) * 256 + h * 32;
    float a = 0.f, b = 0.f;
#pragma unroll
    for (int d = 0; d < 32; d++) {
        float fv = bf2f(feat[base + d]);
        a += fv * al[h * 32 + d];
        b += fv * ar[h * 32 + d];
    }
    el[idx] = f2bf(a);
    er[idx] = f2bf(b);
}

__global__ __launch_bounds__(256) void elr2(const float* __restrict__ feat, const float* __restrict__ al,
                                            const float* __restrict__ ar, float* __restrict__ el,
                                            float* __restrict__ er, int n) {
    int idx = blockIdx.x * 256 + threadIdx.x;
    if (idx >= n) return;
    const float* f = feat + (long)idx * 32;
    float a = 0.f, b = 0.f;
#pragma unroll
    for (int d = 0; d < 32; d++) {
        float fv = f[d];
        a += fv * al[d];
        b += fv * ar[d];
    }
    el[idx] = a;
    er[idx] = b;
}

// exp(leaky_relu(l)); logits O(0.1), max-subtraction unnecessary (identical ratios)
__device__ __forceinline__ float edgew(float l) {
    l = (l > 0.f) ? l : 0.2f * l;
    l = fminf(fmaxf(l, -30.f), 30.f);
    return __expf(l);
}

// ---------------- slot-ordered edge weights ----------------
__global__ __launch_bounds__(256) void ew1s_kernel(const int* __restrict__ srcs, const int* __restrict__ dsts,
                                                   const u16* __restrict__ el, const u16* __restrict__ er,
                                                   float* __restrict__ ew, int ES, int N) {
    int idx = blockIdx.x * 256 + threadIdx.x;  // j*8+h
    if (idx >= ES) return;
    int j = idx >> 3, h = idx & 7;
    unsigned s = (unsigned)srcs[j], d = (unsigned)dsts[j];
    float w = 0.f;
    if (s < (unsigned)N && d < (unsigned)N) w = edgew(bf2f(el[s * 8 + h]) + bf2f(er[d * 8 + h]));
    ew[idx] = w;
}

__global__ __launch_bounds__(256) void ew2s_kernel(const int* __restrict__ srcs, const int* __restrict__ dsts,
                                                   const float* __restrict__ el, const float* __restrict__ er,
                                                   float* __restrict__ ew, int E, int N) {
    int j = blockIdx.x * 256 + threadIdx.x;
    if (j >= E) return;
    unsigned s = (unsigned)srcs[j], d = (unsigned)dsts[j];
    float w = 0.f;
    if (s < (unsigned)N && d < (unsigned)N) w = edgew(el[s] + er[d]);
    ew[j] = w;
}

// ---------------- aggregation ----------------
// Wave per node: lane l owns channels 4l..4l+3 (head = l>>3). One ushort4/lane
// = full 512B feat row per wave load. Chain: srcs[j] -> feat only.
__global__ __launch_bounds__(256) void agg1(const u16* __restrict__ feat, const float* __restrict__ ew,
                                            const int* __restrict__ offs, const int* __restrict__ srcs,
                                            u16* __restrict__ rst, int N, int E) {
    int node = blockIdx.x * 4 + (threadIdx.x >> 6);
    int lane = threadIdx.x & 63;
    if (node >= N) return;
    int h = lane >> 3;
    int beg = offs[node], end = offs[node + 1];
    if (beg < 0) beg = 0;
    if (end > E) end = E;
    float ax = 0.f, ay = 0.f, az = 0.f, aw = 0.f, sw = 0.f;
#pragma unroll 2
    for (int j = beg; j < end; j++) {
        unsigned s = (unsigned)srcs[j];
        if (s >= (unsigned)N) continue;
        float w = ew[(long)j * 8 + h];
        ushort4 f4 = *(const ushort4*)(feat + (long)s * 256 + lane * 4);
        sw += w;
        ax += w * bf2f(f4.x);
        ay += w * bf2f(f4.y);
        az += w * bf2f(f4.z);
        aw += w * bf2f(f4.w);
    }
    float inv = 1.f / (sw + 1e-16f);
    ushort4 o;
    o.x = f2bf(ax * inv);
    o.y = f2bf(ay * inv);
    o.z = f2bf(az * inv);
    o.w = f2bf(aw * inv);
    *(ushort4*)(rst + (long)node * 256 + lane * 4) = o;
}

__global__ __launch_bounds__(256) void agg2(const float* __restrict__ feat, const float* __restrict__ ew,
                                            const int* __restrict__ offs, const int* __restrict__ srcs,
                                            float* __restrict__ rst, int N, int E) {
    int t = threadIdx.x;
    int node = blockIdx.x * 8 + (t >> 5);
    int d = t & 31;
    if (node >= N) return;
    int beg = offs[node], end = offs[node + 1];
    if (beg < 0) beg = 0;
    if (end > E) end = E;
    float acc = 0.f, sw = 0.f;
#pragma unroll 2
    for (int j = beg; j < end; j++) {
        unsigned s = (unsigned)srcs[j];
        if (s >= (unsigned)N) continue;
        float w = ew[j];
        sw += w;
        acc += w * feat[(long)s * 32 + d];
    }
    rst[(long)node * 32 + d] = acc / (sw + 1e-16f);
}

// ---------------- batchnorm stats (block-contiguous rows) ----------------
__global__ __launch_bounds__(256) void bn_stats256(const u16* __restrict__ X, float* __restrict__ stats,
                                                   int rows, int RPB) {
    int t = threadIdx.x;
    int rbeg = blockIdx.x * RPB;
    int rend = rbeg + RPB;
    if (rend > rows) rend = rows;
    float s = 0.f, s2 = 0.f;
    for (int r = rbeg; r < rend; r++) {
        float x = bf2f(X[(long)r * 256 + t]);
        s += x;
        s2 += x * x;
    }
    atomicAdd(&stats[t], s);
    atomicAdd(&stats[256 + t], s2);
}

__global__ __launch_bounds__(256) void bn_stats32(const float* __restrict__ X, float* __restrict__ stats,
                                                  int rows, int RPB) {
    __shared__ float ss[256], ss2[256];
    int t = threadIdx.x, c = t & 31, rs = t >> 5;
    int rbeg = blockIdx.x * RPB;
    int rend = rbeg + RPB;
    if (rend > rows) rend = rows;
    float s = 0.f, s2 = 0.f;
    for (int r = rbeg + rs; r < rend; r += 8) {
        float x = X[(long)r * 32 + c];
        s += x;
        s2 += x * x;
    }
    ss[t] = s;
    ss2[t] = s2;
    __syncthreads();
    if (t < 32) {
        for (int j = 32; j < 256; j += 32) { s += ss[t + j]; s2 += ss2[t + j]; }
        atomicAdd(&stats[c], s);
        atomicAdd(&stats[32 + c], s2);
    }
}

__global__ __launch_bounds__(256) void bn_apply1(const u16* __restrict__ rst, const float* __restrict__ stats,
                                                 const float* __restrict__ g, const float* __restrict__ b,
                                                 u16* __restrict__ hh, int total, float invN) {
    int idx = blockIdx.x * 256 + threadIdx.x;
    if (idx >= total) return;
    int c = idx & 255;
    float mu = stats[c] * invN;
    float var = fmaxf(stats[256 + c] * invN - mu * mu, 0.f);
    float y = g[c] * (bf2f(rst[idx]) - mu) * rsqrtf(var + 1e-5f) + b[c];
    y = (y > 0.f) ? y : expm1f(y);      // elu
    hh[idx] = f2bf(bf2f(hh[idx]) + y);  // residual
}

// FINAL OUTPUT: float32 (reference's output dtype)
__global__ __launch_bounds__(256) void bn_apply2(const float* __restrict__ rst, const float* __restrict__ stats,
                                                 const float* __restrict__ g, const float* __restrict__ b,
                                                 float* __restrict__ out, int total, float invN) {
    int idx = blockIdx.x * 256 + threadIdx.x;
    if (idx >= total) return;
    int c = idx & 31;
    float mu = stats[c] * invN;
    float var = fmaxf(stats[32 + c] * invN - mu * mu, 0.f);
    float y = g[c] * (rst[idx] - mu) * rsqrtf(var + 1e-5f) + b[c];
    y = (y > 0.f) ? y : expm1f(y);
    out[idx] = y;
}

extern "C" void kernel_launch(void* const* d_in, const int* in_sizes, int n_in, void* d_out, int out_size, void* d_ws,
                              size_t ws_size, hipStream_t stream) {
    const int N = out_size / ODIM;
    const int E = in_sizes[2];

    const int* src = (const int*)d_in[2];
    const int* dst = (const int*)d_in[3];
    const float* in_h = (const float*)d_in[0];
    const float* W_emb = (const float*)d_in[4];  const float* b_emb = (const float*)d_in[5];
    const float* fc1 = (const float*)d_in[18];   const float* al1 = (const float*)d_in[19];
    const float* ar1 = (const float*)d_in[20];
    const float* g1 = (const float*)d_in[21];    const float* b1 = (const float*)d_in[22];
    const float* fc2 = (const float*)d_in[23];   const float* al2 = (const float*)d_in[24];
    const float* ar2 = (const float*)d_in[25];
    const float* g2 = (const float*)d_in[26];    const float* b2 = (const float*)d_in[27];
    float* out = (float*)d_out;

    // ---- ws layout (~21 MB) ----
    char* base = (char*)d_ws;
    size_t off = 0;
    auto alloc = [&](size_t bytes) { void* p = base + off; off += (bytes + 63) & ~63ull; return p; };
    u16* hh    = (u16*)alloc((size_t)N * HDIM * 2);
    char* regB = (char*)alloc((size_t)N * HDIM * 2);
    u16* rst   = (u16*)alloc((size_t)N * HDIM * 2);
    char* regD = (char*)alloc((size_t)N * NHEADS * 2);
    char* regE = (char*)alloc((size_t)N * NHEADS * 2);
    float* stats = (float*)alloc((2 * HDIM + 2 * ODIM) * 4);
    int* offs  = (int*)alloc((size_t)(N + 1) * 4);
    int* srcs  = (int*)alloc((size_t)E * 4);
    int* dsts  = (int*)alloc((size_t)E * 4);
    float* ew1 = (float*)alloc((size_t)E * NHEADS * 4);

    u16* feat1 = (u16*)regB;
    int* deg = (int*)regD;
    int* cursor = (int*)regE;
    u16* el1 = (u16*)regD;
    u16* er1 = (u16*)regE;
    float* feat2 = (float*)regB;
    float* rst2 = feat2 + (size_t)N * ODIM;
    float* el2 = rst2 + (size_t)N * ODIM;
    float* er2 = el2 + N;
    float* stats2 = stats + 2 * HDIM;
    float* ew2 = ew1;

    hipMemsetAsync(deg, 0, (size_t)N * sizeof(int), stream);
    hipMemsetAsync(stats, 0, (2 * HDIM + 2 * ODIM) * sizeof(float), stream);

    // ---- CSR by dst ----
    deg_kernel<<<(E + 255) / 256, 256, 0, stream>>>(dst, deg, E, N);
    scan_kernel<<<1, 256, 0, stream>>>(deg, offs, cursor, N);
    fill_kernel<<<(E + 255) / 256, 256, 0, stream>>>(src, dst, cursor, srcs, dsts, E, N);

    // ---- embedding ----
    gemm_rb<128, float><<<(N + 15) / 16, 256, 0, stream>>>(in_h, W_emb, b_emb, hh, N);

    // ---- GAT layer 1 (8 heads x 32, residual) ----
    gemm_rb<256, u16><<<(N + 15) / 16, 256, 0, stream>>>(hh, fc1, nullptr, feat1, N);
    elr1<<<(N * 8 + 255) / 256, 256, 0, stream>>>(feat1, al1, ar1, el1, er1, N * 8);
    ew1s_kernel<<<(E * 8 + 255) / 256, 256, 0, stream>>>(srcs, dsts, el1, er1, ew1, E * 8, N);
    agg1<<<(N + 3) / 4, 256, 0, stream>>>(feat1, ew1, offs, srcs, rst, N, E);
    bn_stats256<<<(N + 39) / 40, 256, 0, stream>>>(rst, stats, N, 40);
    bn_apply1<<<(N * HDIM + 255) / 256, 256, 0, stream>>>(rst, stats, g1, b1, hh, N * HDIM, 1.f / N);

    // ---- GAT layer 2 (1 head x 32, no residual) ----
    gemm_fc2<<<(N + 7) / 8, 256, 0, stream>>>(hh, fc2, feat2, N);
    elr2<<<(N + 255) / 256, 256, 0, stream>>>(feat2, al2, ar2, el2, er2, N);
    ew2s_kernel<<<(E + 255) / 256, 256, 0, stream>>>(srcs, dsts, el2, er2, ew2, E, N);
    agg2<<<(N + 7) / 8, 256, 0, stream>>>(feat2, ew2, offs, srcs, rst2, N, E);
    bn_stats32<<<(N + 63) / 64, 256, 0, stream>>>(rst2, stats2, N, 64);
    bn_apply2<<<(N * ODIM + 255) / 256, 256, 0, stream>>>(rst2, stats2, g2, b2, out, N * ODIM, 1.f / N);
}

// Round 9
// 315.761 us; speedup vs baseline: 2.0755x; 1.0583x over previous
//
#include <hip/hip_runtime.h>
#include <hip/hip_bf16.h>
#include <math.h>

// GATNet: hh = h@W_emb+b_emb -> GAT(8 heads,32,residual) -> GAT(1 head,32) -> out f32.
// Edge-feature branch of the reference is dead code (del e_feat) -> skipped.
// R9: all GEMMs on MFMA 16x16x32 bf16. A-frag = direct ushort8 from row-major bf16
// (m=lane&15, k=quad*8+j); B pre-swizzled to fragment order (one-time, bf16);
// C/D layout col=lane&15, row=quad*4+reg (learn_hip-verified).

#define HDIM 256
#define NHEADS 8
#define ODIM 32

typedef unsigned short u16;
typedef __attribute__((ext_vector_type(8))) short short8;
typedef __attribute__((ext_vector_type(4))) float f32x4;

__device__ __forceinline__ float bf2f(u16 u) { return __uint_as_float(((unsigned)u) << 16); }
__device__ __forceinline__ u16 f2bf(float f) {
    unsigned x = __float_as_uint(f);
    return (u16)((x + 0x7FFFu + ((x >> 16) & 1u)) >> 16);  // RNE
}

// ---------------- prep: convert f32 -> bf16 (vectorized) ----------------
__global__ __launch_bounds__(256) void cvt_bf16(const float* __restrict__ A, u16* __restrict__ O, int n4) {
    int i = blockIdx.x * 256 + threadIdx.x;
    if (i >= n4) return;
    float4 v = ((const float4*)A)[i];
    ushort4 o = {f2bf(v.x), f2bf(v.y), f2bf(v.z), f2bf(v.w)};
    ((ushort4*)O)[i] = o;
}

// ---------------- prep: swizzle B[K][NC] f32 -> MFMA B-fragment order bf16 ----------------
// Bsw[((ct*KB+kb)*64+lane)*8 + j] = bf16(B[kb*32 + (lane>>4)*8 + j][ct*16 + (lane&15)])
template <int K, int NC>
__global__ __launch_bounds__(256) void swzB(const float* __restrict__ B, u16* __restrict__ Bsw) {
    constexpr int KB = K / 32;
    constexpr int TOT = (NC / 16) * KB * 64;
    int idx = blockIdx.x * 256 + threadIdx.x;
    if (idx >= TOT) return;
    int lane = idx & 63;
    int kb = (idx >> 6) % KB;
    int ct = (idx >> 6) / KB;
    int n = ct * 16 + (lane & 15);
    int k0 = kb * 32 + (lane >> 4) * 8;
    u16* dst = Bsw + (size_t)idx * 8;
#pragma unroll
    for (int j = 0; j < 8; j++) dst[j] = f2bf(B[(size_t)(k0 + j) * NC + n]);
}

// ---------------- MFMA GEMM: C[M,NC] = A[M,K](bf16) @ B(swizzled) (+bias) ----------------
// Block = 256 thr = 4 waves; wave handles 16 rows; loops NC/16 col tiles x K/32 k-blocks.
template <int K, int NC, bool BIAS, typename OutT>
__global__ __launch_bounds__(256) void gemm_mfma(const u16* __restrict__ A, const u16* __restrict__ Bsw,
                                                 const float* __restrict__ bias, OutT* __restrict__ C, int M) {
    constexpr int KB = K / 32;
    constexpr int NCT = NC / 16;
    const int lane = threadIdx.x & 63;
    const int r0 = blockIdx.x * 64 + (threadIdx.x >> 6) * 16;
    if (r0 >= M) return;
    const int m = lane & 15, q = lane >> 4;
    const int row = r0 + m;
    short8 a[KB];
#pragma unroll
    for (int kb = 0; kb < KB; kb++) {
        if (row < M) a[kb] = *(const short8*)(A + (size_t)row * K + kb * 32 + q * 8);
        else a[kb] = (short8){0, 0, 0, 0, 0, 0, 0, 0};
    }
    const short8* B8 = (const short8*)Bsw;
#pragma unroll 1
    for (int ct = 0; ct < NCT; ct++) {
        f32x4 acc = {0.f, 0.f, 0.f, 0.f};
#pragma unroll
        for (int kb = 0; kb < KB; kb++)
            acc = __builtin_amdgcn_mfma_f32_16x16x32_bf16(a[kb], B8[(ct * KB + kb) * 64 + lane], acc, 0, 0, 0);
        float bv = BIAS ? bias[ct * 16 + m] : 0.f;
#pragma unroll
        for (int r = 0; r < 4; r++) {
            int ro = r0 + q * 4 + r;
            if (ro < M) {
                float v = acc[r] + bv;
                if constexpr (sizeof(OutT) == 2) C[(size_t)ro * NC + ct * 16 + m] = f2bf(v);
                else C[(size_t)ro * NC + ct * 16 + m] = v;
            }
        }
    }
}

// ---------------- CSR build (dst -> slot-ordered srcs/dsts) ----------------
__global__ __launch_bounds__(256) void deg_kernel(const int* __restrict__ dst, int* __restrict__ deg, int E, int N) {
    int i = blockIdx.x * 256 + threadIdx.x;
    if (i < E) {
        unsigned d = (unsigned)dst[i];
        if (d < (unsigned)N) atomicAdd(&deg[d], 1);
    }
}

__global__ __launch_bounds__(256) void scan_kernel(const int* __restrict__ deg, int* __restrict__ offs,
                                                   int* __restrict__ cursor, int n) {
    __shared__ int part[256];
    int t = threadIdx.x;
    int chunk = (n + 255) / 256;
    int lo = t * chunk, hi = lo + chunk;
    if (hi > n) hi = n;
    if (lo > n) lo = n;
    int s = 0;
    for (int i = lo; i < hi; i++) s += deg[i];
    part[t] = s;
    __syncthreads();
    if (t == 0) {
        int run = 0;
        for (int j = 0; j < 256; j++) { int v = part[j]; part[j] = run; run += v; }
        offs[n] = run;
    }
    __syncthreads();
    int run = part[t];
    for (int i = lo; i < hi; i++) {
        offs[i] = run;
        cursor[i] = run;
        run += deg[i];
    }
}

__global__ __launch_bounds__(256) void fill_kernel(const int* __restrict__ src, const int* __restrict__ dst,
                                                   int* __restrict__ cursor, int* __restrict__ srcs,
                                                   int* __restrict__ dsts, int E, int N) {
    int i = blockIdx.x * 256 + threadIdx.x;
    if (i < E) {
        unsigned d = (unsigned)dst[i];
        if (d < (unsigned)N) {
            int p = atomicAdd(&cursor[d], 1);
            if ((unsigned)p < (unsigned)E) { srcs[p] = src[i]; dsts[p] = (int)d; }
        }
    }
}

// ---------------- attention coefficients ----------------
__global__ __launch_bounds__(256) void elr1(const u16* __restrict__ feat, const float* __restrict__ al,
                                            const float* __restrict__ ar, u16* __restrict__ el,
                                            u16* __restrict__ er, int NH) {
    int idx = blockIdx.x * 256 + threadIdx.x;  // n*8+h
    if (idx >= NH) return;
    int h = idx & 7;
    long base = (long)(idx >> 3) * 256 + h * 32;
    float a = 0.f, b = 0.f;
#pragma unroll
    for (int d = 0; d < 32; d++) {
        float fv = bf2f(feat[base + d]);
        a += fv * al[h * 32 + d];
        b += fv * ar[h * 32 + d];
    }
    el[idx] = f2bf(a);
    er[idx] = f2bf(b);
}

__global__ __launch_bounds__(256) void elr2(const float* __restrict__ feat, const float* __restrict__ al,
                                            const float* __restrict__ ar, float* __restrict__ el,
                                            float* __restrict__ er, int n) {
    int idx = blockIdx.x * 256 + threadIdx.x;
    if (idx >= n) return;
    const float* f = feat + (long)idx * 32;
    float a = 0.f, b = 0.f;
#pragma unroll
    for (int d = 0; d < 32; d++) {
        float fv = f[d];
        a += fv * al[d];
        b += fv * ar[d];
    }
    el[idx] = a;
    er[idx] = b;
}

// exp(leaky_relu(l)); logits O(0.1), max-subtraction unnecessary (identical ratios)
__device__ __forceinline__ float edgew(float l) {
    l = (l > 0.f) ? l : 0.2f * l;
    l = fminf(fmaxf(l, -30.f), 30.f);
    return __expf(l);
}

// ---------------- slot-ordered edge weights ----------------
__global__ __launch_bounds__(256) void ew1s_kernel(const int* __restrict__ srcs, const int* __restrict__ dsts,
                                                   const u16* __restrict__ el, const u16* __restrict__ er,
                                                   float* __restrict__ ew, int ES, int N) {
    int idx = blockIdx.x * 256 + threadIdx.x;  // j*8+h
    if (idx >= ES) return;
    int j = idx >> 3, h = idx & 7;
    unsigned s = (unsigned)srcs[j], d = (unsigned)dsts[j];
    float w = 0.f;
    if (s < (unsigned)N && d < (unsigned)N) w = edgew(bf2f(el[s * 8 + h]) + bf2f(er[d * 8 + h]));
    ew[idx] = w;
}

__global__ __launch_bounds__(256) void ew2s_kernel(const int* __restrict__ srcs, const int* __restrict__ dsts,
                                                   const float* __restrict__ el, const float* __restrict__ er,
                                                   float* __restrict__ ew, int E, int N) {
    int j = blockIdx.x * 256 + threadIdx.x;
    if (j >= E) return;
    unsigned s = (unsigned)srcs[j], d = (unsigned)dsts[j];
    float w = 0.f;
    if (s < (unsigned)N && d < (unsigned)N) w = edgew(el[s] + er[d]);
    ew[j] = w;
}

// ---------------- aggregation ----------------
// Wave per node: lane l owns channels 4l..4l+3 (head = l>>3).
__global__ __launch_bounds__(256) void agg1(const u16* __restrict__ feat, const float* __restrict__ ew,
                                            const int* __restrict__ offs, const int* __restrict__ srcs,
                                            u16* __restrict__ rst, int N, int E) {
    int node = blockIdx.x * 4 + (threadIdx.x >> 6);
    int lane = threadIdx.x & 63;
    if (node >= N) return;
    int h = lane >> 3;
    int beg = offs[node], end = offs[node + 1];
    if (beg < 0) beg = 0;
    if (end > E) end = E;
    float ax = 0.f, ay = 0.f, az = 0.f, aw = 0.f, sw = 0.f;
#pragma unroll 2
    for (int j = beg; j < end; j++) {
        unsigned s = (unsigned)srcs[j];
        if (s >= (unsigned)N) continue;
        float w = ew[(long)j * 8 + h];
        ushort4 f4 = *(const ushort4*)(feat + (long)s * 256 + lane * 4);
        sw += w;
        ax += w * bf2f(f4.x);
        ay += w * bf2f(f4.y);
        az += w * bf2f(f4.z);
        aw += w * bf2f(f4.w);
    }
    float inv = 1.f / (sw + 1e-16f);
    ushort4 o;
    o.x = f2bf(ax * inv);
    o.y = f2bf(ay * inv);
    o.z = f2bf(az * inv);
    o.w = f2bf(aw * inv);
    *(ushort4*)(rst + (long)node * 256 + lane * 4) = o;
}

__global__ __launch_bounds__(256) void agg2(const float* __restrict__ feat, const float* __restrict__ ew,
                                            const int* __restrict__ offs, const int* __restrict__ srcs,
                                            float* __restrict__ rst, int N, int E) {
    int t = threadIdx.x;
    int node = blockIdx.x * 8 + (t >> 5);
    int d = t & 31;
    if (node >= N) return;
    int beg = offs[node], end = offs[node + 1];
    if (beg < 0) beg = 0;
    if (end > E) end = E;
    float acc = 0.f, sw = 0.f;
#pragma unroll 2
    for (int j = beg; j < end; j++) {
        unsigned s = (unsigned)srcs[j];
        if (s >= (unsigned)N) continue;
        float w = ew[j];
        sw += w;
        acc += w * feat[(long)s * 32 + d];
    }
    rst[(long)node * 32 + d] = acc / (sw + 1e-16f);
}

// ---------------- batchnorm stats (block-contiguous rows) ----------------
__global__ __launch_bounds__(256) void bn_stats256(const u16* __restrict__ X, float* __restrict__ stats,
                                                   int rows, int RPB) {
    int t = threadIdx.x;
    int rbeg = blockIdx.x * RPB;
    int rend = rbeg + RPB;
    if (rend > rows) rend = rows;
    float s = 0.f, s2 = 0.f;
    for (int r = rbeg; r < rend; r++) {
        float x = bf2f(X[(long)r * 256 + t]);
        s += x;
        s2 += x * x;
    }
    atomicAdd(&stats[t], s);
    atomicAdd(&stats[256 + t], s2);
}

__global__ __launch_bounds__(256) void bn_stats32(const float* __restrict__ X, float* __restrict__ stats,
                                                  int rows, int RPB) {
    __shared__ float ss[256], ss2[256];
    int t = threadIdx.x, c = t & 31, rs = t >> 5;
    int rbeg = blockIdx.x * RPB;
    int rend = rbeg + RPB;
    if (rend > rows) rend = rows;
    float s = 0.f, s2 = 0.f;
    for (int r = rbeg + rs; r < rend; r += 8) {
        float x = X[(long)r * 32 + c];
        s += x;
        s2 += x * x;
    }
    ss[t] = s;
    ss2[t] = s2;
    __syncthreads();
    if (t < 32) {
        for (int j = 32; j < 256; j += 32) { s += ss[t + j]; s2 += ss2[t + j]; }
        atomicAdd(&stats[c], s);
        atomicAdd(&stats[32 + c], s2);
    }
}

__global__ __launch_bounds__(256) void bn_apply1(const u16* __restrict__ rst, const float* __restrict__ stats,
                                                 const float* __restrict__ g, const float* __restrict__ b,
                                                 u16* __restrict__ hh, int total, float invN) {
    int idx = blockIdx.x * 256 + threadIdx.x;
    if (idx >= total) return;
    int c = idx & 255;
    float mu = stats[c] * invN;
    float var = fmaxf(stats[256 + c] * invN - mu * mu, 0.f);
    float y = g[c] * (bf2f(rst[idx]) - mu) * rsqrtf(var + 1e-5f) + b[c];
    y = (y > 0.f) ? y : expm1f(y);      // elu
    hh[idx] = f2bf(bf2f(hh[idx]) + y);  // residual
}

// FINAL OUTPUT: float32 (reference's output dtype)
__global__ __launch_bounds__(256) void bn_apply2(const float* __restrict__ rst, const float* __restrict__ stats,
                                                 const float* __restrict__ g, const float* __restrict__ b,
                                                 float* __restrict__ out, int total, float invN) {
    int idx = blockIdx.x * 256 + threadIdx.x;
    if (idx >= total) return;
    int c = idx & 31;
    float mu = stats[c] * invN;
    float var = fmaxf(stats[32 + c] * invN - mu * mu, 0.f);
    float y = g[c] * (rst[idx] - mu) * rsqrtf(var + 1e-5f) + b[c];
    y = (y > 0.f) ? y : expm1f(y);
    out[idx] = y;
}

extern "C" void kernel_launch(void* const* d_in, const int* in_sizes, int n_in, void* d_out, int out_size, void* d_ws,
                              size_t ws_size, hipStream_t stream) {
    const int N = out_size / ODIM;
    const int E = in_sizes[2];

    const int* src = (const int*)d_in[2];
    const int* dst = (const int*)d_in[3];
    const float* in_h = (const float*)d_in[0];
    const float* W_emb = (const float*)d_in[4];  const float* b_emb = (const float*)d_in[5];
    const float* fc1 = (const float*)d_in[18];   const float* al1 = (const float*)d_in[19];
    const float* ar1 = (const float*)d_in[20];
    const float* g1 = (const float*)d_in[21];    const float* b1 = (const float*)d_in[22];
    const float* fc2 = (const float*)d_in[23];   const float* al2 = (const float*)d_in[24];
    const float* ar2 = (const float*)d_in[25];
    const float* g2 = (const float*)d_in[26];    const float* b2 = (const float*)d_in[27];
    float* out = (float*)d_out;

    // ---- ws layout (~24 MB) ----
    char* base = (char*)d_ws;
    size_t off = 0;
    auto alloc = [&](size_t bytes) { void* p = base + off; off += (bytes + 63) & ~63ull; return p; };
    u16* hh    = (u16*)alloc((size_t)N * HDIM * 2);
    char* regB = (char*)alloc((size_t)N * HDIM * 2);
    u16* rst   = (u16*)alloc((size_t)N * HDIM * 2);
    char* regD = (char*)alloc((size_t)N * NHEADS * 2);
    char* regE = (char*)alloc((size_t)N * NHEADS * 2);
    float* stats = (float*)alloc((2 * HDIM + 2 * ODIM) * 4);
    int* offs  = (int*)alloc((size_t)(N + 1) * 4);
    int* srcs  = (int*)alloc((size_t)E * 4);
    int* dsts  = (int*)alloc((size_t)E * 4);
    float* ew1 = (float*)alloc((size_t)E * NHEADS * 4);
    u16* Ah      = (u16*)alloc((size_t)N * 128 * 2);   // in_h converted to bf16
    u16* Bsw_emb = (u16*)alloc((size_t)128 * 256 * 2);
    u16* Bsw_fc1 = (u16*)alloc((size_t)256 * 256 * 2);
    u16* Bsw_fc2 = (u16*)alloc((size_t)256 * 32 * 2);

    u16* feat1 = (u16*)regB;
    int* deg = (int*)regD;
    int* cursor = (int*)regE;
    u16* el1 = (u16*)regD;
    u16* er1 = (u16*)regE;
    float* feat2 = (float*)regB;
    float* rst2 = feat2 + (size_t)N * ODIM;
    float* el2 = rst2 + (size_t)N * ODIM;
    float* er2 = el2 + N;
    float* stats2 = stats + 2 * HDIM;
    float* ew2 = ew1;

    hipMemsetAsync(deg, 0, (size_t)N * sizeof(int), stream);
    hipMemsetAsync(stats, 0, (2 * HDIM + 2 * ODIM) * sizeof(float), stream);

    // ---- prep: A conversion + B swizzles (tiny) ----
    cvt_bf16<<<(N * 128 / 4 + 255) / 256, 256, 0, stream>>>(in_h, Ah, N * 128 / 4);
    swzB<128, 256><<<16, 256, 0, stream>>>(W_emb, Bsw_emb);
    swzB<256, 256><<<32, 256, 0, stream>>>(fc1, Bsw_fc1);
    swzB<256, 32><<<4, 256, 0, stream>>>(fc2, Bsw_fc2);

    // ---- CSR by dst ----
    deg_kernel<<<(E + 255) / 256, 256, 0, stream>>>(dst, deg, E, N);
    scan_kernel<<<1, 256, 0, stream>>>(deg, offs, cursor, N);
    fill_kernel<<<(E + 255) / 256, 256, 0, stream>>>(src, dst, cursor, srcs, dsts, E, N);

    // ---- embedding (MFMA) ----
    gemm_mfma<128, 256, true, u16><<<(N + 63) / 64, 256, 0, stream>>>(Ah, Bsw_emb, b_emb, hh, N);

    // ---- GAT layer 1 (8 heads x 32, residual) ----
    gemm_mfma<256, 256, false, u16><<<(N + 63) / 64, 256, 0, stream>>>(hh, Bsw_fc1, nullptr, feat1, N);
    elr1<<<(N * 8 + 255) / 256, 256, 0, stream>>>(feat1, al1, ar1, el1, er1, N * 8);
    ew1s_kernel<<<(E * 8 + 255) / 256, 256, 0, stream>>>(srcs, dsts, el1, er1, ew1, E * 8, N);
    agg1<<<(N + 3) / 4, 256, 0, stream>>>(feat1, ew1, offs, srcs, rst, N, E);
    bn_stats256<<<(N + 39) / 40, 256, 0, stream>>>(rst, stats, N, 40);
    bn_apply1<<<(N * HDIM + 255) / 256, 256, 0, stream>>>(rst, stats, g1, b1, hh, N * HDIM, 1.f / N);

    // ---- GAT layer 2 (1 head x 32, no residual) ----
    gemm_mfma<256, 32, false, float><<<(N + 63) / 64, 256, 0, stream>>>(hh, Bsw_fc2, nullptr, feat2, N);
    elr2<<<(N + 255) / 256, 256, 0, stream>>>(feat2, al2, ar2, el2, er2, N);
    ew2s_kernel<<<(E + 255) / 256, 256, 0, stream>>>(srcs, dsts, el2, er2, ew2, E, N);
    agg2<<<(N + 7) / 8, 256, 0, stream>>>(feat2, ew2, offs, srcs, rst2, N, E);
    bn_stats32<<<(N + 63) / 64, 256, 0, stream>>>(rst2, stats2, N, 64);
    bn_apply2<<<(N * ODIM + 255) / 256, 256, 0, stream>>>(rst2, stats2, g2, b2, out, N * ODIM, 1.f / N);
}